// Round 8
// baseline (170.521 us; speedup 1.0000x reference)
//
#include <hip/hip_runtime.h>

// DCNv2 forward = bf16-NHWC transpose + 2-phase im2col + MFMA GEMM (32x32 wave tile).
#define N_    4
#define C_    64
#define H_    128
#define W_    128
#define KW_   3
#define K_    9
#define COUT_ 64
#define HW_   (H_ * W_)     // 16384
#define NPIX  (N_ * HW_)    // 65536
#define KK_   (C_ * K_)     // 576

typedef short v8s __attribute__((ext_vector_type(8)));   // 8 bf16 (4 VGPRs)
typedef float v4f __attribute__((ext_vector_type(4)));   // MFMA C/D
typedef int   v4i __attribute__((ext_vector_type(4)));
typedef unsigned short u16;

static __device__ __forceinline__ u16 f2bf(float f) {
    union { float f; unsigned int u; } v; v.f = f;
    unsigned int r = v.u + 0x7FFFu + ((v.u >> 16) & 1u);   // RNE
    return (u16)(r >> 16);
}
static __device__ __forceinline__ float bf2f(u16 b) {
    union { unsigned int u; float f; } v; v.u = ((unsigned int)b) << 16;
    return v.f;
}

// ---------------------------------------------------------------------------
// wA3[o][k], k = tap*64 + c  (matches cols2 k-ordering).  64x576 bf16, 73.7 KB.
// ---------------------------------------------------------------------------
__global__ void build_wA(const float* __restrict__ w, u16* __restrict__ wA3) {
    int tid = blockIdx.x * blockDim.x + threadIdx.x;     // 0 .. 36863
    if (tid >= COUT_ * KK_) return;
    int k   = tid % KK_;          // tap*64 + c
    int o   = tid / KK_;
    int c   = k & 63;
    int tap = k >> 6;
    wA3[tid] = f2bf(w[o * (C_ * K_) + c * K_ + tap]);
}

// ---------------------------------------------------------------------------
// NCHW fp32 -> NHWC bf16 transpose: xh[n][hw][c] = bf16(x[n][c][hw]).
// bf16 xh halves im2col's corner-load cache-line traffic (256B -> 128B).
// ---------------------------------------------------------------------------
__global__ __launch_bounds__(256) void transpose_x(
    const float* __restrict__ x, u16* __restrict__ xh)
{
    const int n   = blockIdx.x >> 8;            // 4 images x 256 hw-tiles
    const int hw0 = (blockIdx.x & 255) * 64;
    const int j   = threadIdx.x & 63;           // lane
    const int r0  = threadIdx.x >> 6;           // 0..3

    __shared__ float tile[64][65];              // [hw][c], pad -> conflict-free
    const float* xb = x + n * (C_ * HW_);
#pragma unroll
    for (int i = 0; i < 16; ++i) {
        const int c = i * 4 + r0;
        tile[j][c] = xb[c * HW_ + hw0 + j];     // lane j = hw: coalesced 256B
    }
    __syncthreads();
    u16* xo = xh + ((size_t)n * HW_ + hw0) * 64;
#pragma unroll
    for (int i = 0; i < 16; ++i) {
        const int hr = i * 4 + r0;
        xo[hr * 64 + j] = f2bf(tile[hr][j]);    // lane j = c: coalesced 128B
    }
}

// ---------------------------------------------------------------------------
// im2col, 2-phase (R7-verified structure). Wave = 8 px x 9 taps = 72 entries.
// Phase 1 (lane = entry): bilinear coefs {f00..f11, i00..i11} -> 32B to LDS.
// Phase 2 (lane = channel): 2 broadcast ds_read_b128 + 4 wave-uniform 128B
// bf16 corner loads (2 lines each, half of R7's fp32) + lerp + 128B store.
// ---------------------------------------------------------------------------
__global__ __launch_bounds__(256) void im2col(
    const u16* __restrict__ xh,        // (N, HW, C) bf16
    const float* __restrict__ offset,  // (N, 2*K, H, W)
    const float* __restrict__ mask,    // (N, K, H, W)
    u16* __restrict__ cols2)           // (NPIX, KK)
{
    const int lane = threadIdx.x & 63;
    const int wv   = threadIdx.x >> 6;
    const int lb   = (blockIdx.x & 7) * 256 + (blockIdx.x >> 3);   // XCD swizzle
    const int px0  = lb * 32 + wv * 8;          // wave's 8 pixels
    const int n    = px0 >> 14;                 // 32 | HW_: uniform per wave

    __shared__ float lds[4][72][8];             // 9216 B: [wave][entry][f4,i4]

    // ---- phase 1: lane-parallel coefficient computation ----
#pragma unroll
    for (int rep = 0; rep < 2; ++rep) {
        const int e = rep * 64 + lane;
        if (e < 72) {
            const int p  = e / 9;               // magic-mul
            const int t  = e - p * 9;
            const int hw = (px0 + p) & (HW_ - 1);
            const int ho = hw >> 7;
            const int wo = hw & (W_ - 1);
            const int ky = t / KW_;
            const int kx = t - ky * KW_;

            const float offy = offset[n * (2 * K_ * HW_) + (2 * t + 0) * HW_ + hw];
            const float offx = offset[n * (2 * K_ * HW_) + (2 * t + 1) * HW_ + hw];
            const float mval = mask[n * (K_ * HW_) + t * HW_ + hw];

            const float py = (float)(ho - 1 + ky) + offy;   // stride=1,pad=1,dil=1
            const float qx = (float)(wo - 1 + kx) + offx;
            const float y0f = floorf(py), x0f = floorf(qx);
            const float ly = py - y0f, lx = qx - x0f;
            const int y0 = (int)y0f, x0 = (int)x0f;
            const int y1 = y0 + 1,   x1 = x0 + 1;
            const bool vy0 = (y0 >= 0) & (y0 < H_);
            const bool vy1 = (y1 >= 0) & (y1 < H_);
            const bool vx0 = (x0 >= 0) & (x0 < W_);
            const bool vx1 = (x1 >= 0) & (x1 < W_);
            const int cy0 = min(max(y0, 0), H_ - 1);
            const int cy1 = min(max(y1, 0), H_ - 1);
            const int cx0 = min(max(x0, 0), W_ - 1);
            const int cx1 = min(max(x1, 0), W_ - 1);

            float* q = &lds[wv][e][0];
            q[0] = (1.f - ly) * (1.f - lx) * mval * ((vy0 && vx0) ? 1.f : 0.f);
            q[1] = (1.f - ly) * lx         * mval * ((vy0 && vx1) ? 1.f : 0.f);
            q[2] = ly         * (1.f - lx) * mval * ((vy1 && vx0) ? 1.f : 0.f);
            q[3] = ly         * lx         * mval * ((vy1 && vx1) ? 1.f : 0.f);
            int* qi = (int*)q;
            qi[4] = cy0 * W_ + cx0;
            qi[5] = cy0 * W_ + cx1;
            qi[6] = cy1 * W_ + cx0;
            qi[7] = cy1 * W_ + cx1;
        }
    }
    __syncthreads();

    // ---- phase 2: lane = channel, wave-uniform bf16 gathers ----
    const u16* xb = xh + ((size_t)n * HW_) * 64 + lane;
    for (int p = 0; p < 8; ++p) {
        const int px = px0 + p;
        u16* cp = cols2 + (size_t)px * KK_ + lane;
#pragma unroll
        for (int t = 0; t < K_; ++t) {
            const float* q = &lds[wv][p * 9 + t][0];
            const v4f f = *(const v4f*)q;                   // broadcast b128
            const v4i o = *(const v4i*)(q + 4);             // broadcast b128

            const float v00 = bf2f(xb[(size_t)o.x * 64]);   // 128B uniform loads
            const float v01 = bf2f(xb[(size_t)o.y * 64]);
            const float v10 = bf2f(xb[(size_t)o.z * 64]);
            const float v11 = bf2f(xb[(size_t)o.w * 64]);

            const float val = fmaf(f.x, v00, fmaf(f.y, v01,
                              fmaf(f.z, v10, f.w * v11)));
            cp[t * 64] = f2bf(val);                         // 128B wave store
        }
    }
}

// ---------------------------------------------------------------------------
// GEMM: out[o, px] = sum_k wA3[o,k] * cols2[px,k].  M=64, K=576, N=65536.
// Block = 4 waves covering 64cout x 64px; wave tile = 32cout x 32px (2x2 of
// 16x16x32). Grid 1024 -> 4 blocks/CU = 4 waves/SIMD (2x R7: hides the
// cols2 B-stream latency). Same XCD swizzle as im2col -> cols2 slab affinity.
// No LDS, no barriers.
// ---------------------------------------------------------------------------
__global__ __launch_bounds__(256) void gemm_mfma(
    const u16* __restrict__ cols2,     // (NPIX, KK)
    const u16* __restrict__ wA3,       // (COUT, KK)
    const float* __restrict__ bias,
    float* __restrict__ out)           // (N, Cout, H, W)
{
    const int lane = threadIdx.x & 63;
    const int wv   = threadIdx.x >> 6;
    const int quad = lane >> 4;
    const int l16  = lane & 15;

    const int lb  = (blockIdx.x & 7) * 128 + (blockIdx.x >> 3);  // match im2col
    const int pxb = lb * 64;
    const int n   = pxb >> 14;                   // 64 | HW_: never crosses
    const int mb  = (wv & 1) * 32;               // wave's cout half
    const int pxw = pxb + (wv >> 1) * 32;        // wave's 32-pixel strip
    const int hwb = pxw & (HW_ - 1);

    v4f acc[2][2];
#pragma unroll
    for (int mh = 0; mh < 2; ++mh)
#pragma unroll
        for (int nh = 0; nh < 2; ++nh)
            acc[mh][nh] = (v4f){0.f, 0.f, 0.f, 0.f};

    const u16* bp0 = cols2 + (size_t)(pxw + l16) * KK_ + quad * 8;
    const u16* bp1 = bp0 + 16 * KK_;
    const u16* ap  = wA3 + (size_t)(mb + l16) * KK_ + quad * 8;

    for (int kc = 0; kc < KK_ / 32; ++kc) {      // 18 chunks of 32
        v8s bfr[2];
        bfr[0] = *(const v8s*)(bp0 + kc * 32);
        bfr[1] = *(const v8s*)(bp1 + kc * 32);
        v8s afr[2];
        afr[0] = *(const v8s*)(ap + kc * 32);
        afr[1] = *(const v8s*)(ap + 16 * KK_ + kc * 32);
#pragma unroll
        for (int mh = 0; mh < 2; ++mh)
#pragma unroll
            for (int nh = 0; nh < 2; ++nh)
                acc[mh][nh] = __builtin_amdgcn_mfma_f32_16x16x32_bf16(
                    afr[mh], bfr[nh], acc[mh][nh], 0, 0, 0);
    }

    // D layout (R4-verified): col = l16 (px), row = quad*4 + r (cout)
    float* outb = out + n * (COUT_ * HW_);
#pragma unroll
    for (int mh = 0; mh < 2; ++mh)
#pragma unroll
        for (int nh = 0; nh < 2; ++nh)
#pragma unroll
            for (int r = 0; r < 4; ++r) {
                const int m = mb + mh * 16 + quad * 4 + r;
                outb[m * HW_ + hwb + nh * 16 + l16] = acc[mh][nh][r] + bias[m];
            }
}

// ---------------------------------------------------------------------------
// Fallback (ws too small): R3-style direct fp32 kernel, no ws needed.
// ---------------------------------------------------------------------------
__global__ __launch_bounds__(256) void dcn_fallback(
    const float* __restrict__ x, const float* __restrict__ offset,
    const float* __restrict__ mask, const float* __restrict__ wptr,
    const float* __restrict__ bias, float* __restrict__ out)
{
    const int pix = blockIdx.x * 256 + threadIdx.x;
    const int n = pix >> 14, hw = pix & (HW_ - 1);
    const int ho = hw >> 7,  wo = hw & (W_ - 1);
    float acc[COUT_];
#pragma unroll
    for (int o = 0; o < COUT_; ++o) acc[o] = bias[o];
    const float* xn   = x + n * (C_ * HW_);
    const float* offn = offset + n * (2 * K_ * HW_) + hw;
    const float* mn   = mask + n * (K_ * HW_) + hw;
    for (int ct = 0; ct < C_; ct += 8) {
        for (int k = 0; k < K_; ++k) {
            const int ky = k / KW_, kx = k - ky * KW_;
            const float off_y = offn[(2 * k + 0) * HW_];
            const float off_x = offn[(2 * k + 1) * HW_];
            const float m = mn[k * HW_];
            const float py = (float)(ho - 1 + ky) + off_y;
            const float px = (float)(wo - 1 + kx) + off_x;
            const float y0f = floorf(py), x0f = floorf(px);
            const float ly = py - y0f, lx = px - x0f;
            const int y0 = (int)y0f, x0 = (int)x0f, y1 = y0 + 1, x1 = x0 + 1;
            const bool vy0 = (y0 >= 0) & (y0 < H_), vy1 = (y1 >= 0) & (y1 < H_);
            const bool vx0 = (x0 >= 0) & (x0 < W_), vx1 = (x1 >= 0) & (x1 < W_);
            const int cy0 = min(max(y0, 0), H_ - 1), cy1 = min(max(y1, 0), H_ - 1);
            const int cx0 = min(max(x0, 0), W_ - 1), cx1 = min(max(x1, 0), W_ - 1);
            const int i00 = cy0 * W_ + cx0, i01 = cy0 * W_ + cx1;
            const int i10 = cy1 * W_ + cx0, i11 = cy1 * W_ + cx1;
            const float f00 = (1.f - ly) * (1.f - lx) * m * ((vy0 && vx0) ? 1.f : 0.f);
            const float f01 = (1.f - ly) * lx * m * ((vy0 && vx1) ? 1.f : 0.f);
            const float f10 = ly * (1.f - lx) * m * ((vy1 && vx0) ? 1.f : 0.f);
            const float f11 = ly * lx * m * ((vy1 && vx1) ? 1.f : 0.f);
            for (int cc = 0; cc < 8; ++cc) {
                const int c = ct + cc;
                const float* xc = xn + c * HW_;
                const float val = fmaf(f00, xc[i00], fmaf(f01, xc[i01],
                                  fmaf(f10, xc[i10], f11 * xc[i11])));
#pragma unroll
                for (int o = 0; o < COUT_; ++o)
                    acc[o] = fmaf(wptr[o * (C_ * K_) + c * K_ + k], val, acc[o]);
            }
        }
    }
    float* outp = out + n * (COUT_ * HW_) + hw;
#pragma unroll
    for (int o = 0; o < COUT_; ++o) outp[o * HW_] = acc[o];
}

extern "C" void kernel_launch(void* const* d_in, const int* in_sizes, int n_in,
                              void* d_out, int out_size, void* d_ws, size_t ws_size,
                              hipStream_t stream) {
    const float* x      = (const float*)d_in[0];
    const float* offset = (const float*)d_in[1];
    const float* mask   = (const float*)d_in[2];
    const float* weight = (const float*)d_in[3];
    const float* bias   = (const float*)d_in[4];
    float* out = (float*)d_out;

    const size_t cols_bytes = (size_t)NPIX * KK_ * sizeof(u16);      // 75.5 MB
    const size_t xh_bytes   = (size_t)NPIX * C_ * sizeof(u16);       // 8.4 MB
    const size_t wA_bytes   = (size_t)COUT_ * KK_ * sizeof(u16);     // 73.7 KB

    if (ws_size >= cols_bytes + xh_bytes + wA_bytes) {
        u16* cols2 = (u16*)d_ws;
        u16* xh    = (u16*)((char*)d_ws + cols_bytes);
        u16* wA3   = (u16*)((char*)d_ws + cols_bytes + xh_bytes);
        build_wA<<<(COUT_ * KK_ + 255) / 256, 256, 0, stream>>>(weight, wA3);
        transpose_x<<<N_ * 256, 256, 0, stream>>>(x, xh);
        im2col<<<NPIX / 32, 256, 0, stream>>>(xh, offset, mask, cols2);
        gemm_mfma<<<NPIX / 64, 256, 0, stream>>>(cols2, wA3, bias, out);
    } else {
        dcn_fallback<<<NPIX / 256, 256, 0, stream>>>(x, offset, mask, weight, bias, out);
    }
}

// Round 9
// 148.407 us; speedup vs baseline: 1.1490x; 1.1490x over previous
//
#include <hip/hip_runtime.h>

// DCNv2 forward = prep (weight repack + NHWC transpose) + 2-phase im2col
// (fp32 xh — R8's bf16 xh regressed: u16 lane loads -> VGPR 16, no ILP)
// + MFMA GEMM (32x32 wave tile, 4 blocks/CU).
#define N_    4
#define C_    64
#define H_    128
#define W_    128
#define KW_   3
#define K_    9
#define COUT_ 64
#define HW_   (H_ * W_)     // 16384
#define NPIX  (N_ * HW_)    // 65536
#define KK_   (C_ * K_)     // 576

typedef short v8s __attribute__((ext_vector_type(8)));   // 8 bf16 (4 VGPRs)
typedef float v4f __attribute__((ext_vector_type(4)));   // MFMA C/D
typedef int   v4i __attribute__((ext_vector_type(4)));
typedef unsigned short u16;

static __device__ __forceinline__ u16 f2bf(float f) {
    union { float f; unsigned int u; } v; v.f = f;
    unsigned int r = v.u + 0x7FFFu + ((v.u >> 16) & 1u);   // RNE
    return (u16)(r >> 16);
}

// ---------------------------------------------------------------------------
// prep: one dispatch doing both prologue jobs.
//   blocks 0..1023  : NCHW->NHWC fp32 transpose xh[n][hw][c] (LDS-tiled 64x64)
//   blocks 1024..1167: wA3[o][k] = bf16(weight[o][c][tap]), k = tap*64+c
// ---------------------------------------------------------------------------
__global__ __launch_bounds__(256) void prep(
    const float* __restrict__ x, float* __restrict__ xh,
    const float* __restrict__ w, u16* __restrict__ wA3)
{
    if (blockIdx.x < 1024) {
        const int n   = blockIdx.x >> 8;            // 4 images x 256 hw-tiles
        const int hw0 = (blockIdx.x & 255) * 64;
        const int j   = threadIdx.x & 63;           // lane
        const int r0  = threadIdx.x >> 6;           // 0..3

        __shared__ float tile[64][65];              // [hw][c], pad -> conflict-free
        const float* xb = x + n * (C_ * HW_);
#pragma unroll
        for (int i = 0; i < 16; ++i) {
            const int c = i * 4 + r0;
            tile[j][c] = xb[c * HW_ + hw0 + j];     // lane j = hw: coalesced 256B
        }
        __syncthreads();
        float* xo = xh + ((size_t)n * HW_ + hw0) * 64;
#pragma unroll
        for (int i = 0; i < 16; ++i) {
            const int hr = i * 4 + r0;
            xo[hr * 64 + j] = tile[hr][j];          // lane j = c: coalesced 256B
        }
    } else {
        const int tid = (blockIdx.x - 1024) * 256 + threadIdx.x;  // 0..36863
        if (tid < COUT_ * KK_) {
            const int k   = tid % KK_;              // tap*64 + c
            const int o   = tid / KK_;
            const int c   = k & 63;
            const int tap = k >> 6;
            wA3[tid] = f2bf(w[o * (C_ * K_) + c * K_ + tap]);
        }
    }
}

// ---------------------------------------------------------------------------
// im2col, 2-phase (R7-verified). Wave = 8 px x 9 taps = 72 entries.
// Phase 1 (lane = entry): bilinear coefs {f00..f11, i00..i11} -> 32B to LDS.
// Phase 2 (lane = channel): 2 broadcast ds_read_b128 + 4 wave-uniform 256B
// fp32 corner loads + lerp + 128B bf16 store. (fp32 loads: keep per-lane
// accesses >=32-bit — R8's u16 loads collapsed VGPR/ILP.)
// ---------------------------------------------------------------------------
__global__ __launch_bounds__(256) void im2col(
    const float* __restrict__ xh,      // (N, HW, C) fp32
    const float* __restrict__ offset,  // (N, 2*K, H, W)
    const float* __restrict__ mask,    // (N, K, H, W)
    u16* __restrict__ cols2)           // (NPIX, KK)
{
    const int lane = threadIdx.x & 63;
    const int wv   = threadIdx.x >> 6;
    const int lb   = (blockIdx.x & 7) * 256 + (blockIdx.x >> 3);   // XCD swizzle
    const int px0  = lb * 32 + wv * 8;          // wave's 8 pixels
    const int n    = px0 >> 14;                 // 32 | HW_: uniform per wave

    __shared__ float lds[4][72][8];             // 9216 B: [wave][entry][f4,i4]

    // ---- phase 1: lane-parallel coefficient computation ----
#pragma unroll
    for (int rep = 0; rep < 2; ++rep) {
        const int e = rep * 64 + lane;
        if (e < 72) {
            const int p  = e / 9;               // magic-mul
            const int t  = e - p * 9;
            const int hw = (px0 + p) & (HW_ - 1);
            const int ho = hw >> 7;
            const int wo = hw & (W_ - 1);
            const int ky = t / KW_;
            const int kx = t - ky * KW_;

            const float offy = offset[n * (2 * K_ * HW_) + (2 * t + 0) * HW_ + hw];
            const float offx = offset[n * (2 * K_ * HW_) + (2 * t + 1) * HW_ + hw];
            const float mval = mask[n * (K_ * HW_) + t * HW_ + hw];

            const float py = (float)(ho - 1 + ky) + offy;   // stride=1,pad=1,dil=1
            const float qx = (float)(wo - 1 + kx) + offx;
            const float y0f = floorf(py), x0f = floorf(qx);
            const float ly = py - y0f, lx = qx - x0f;
            const int y0 = (int)y0f, x0 = (int)x0f;
            const int y1 = y0 + 1,   x1 = x0 + 1;
            const bool vy0 = (y0 >= 0) & (y0 < H_);
            const bool vy1 = (y1 >= 0) & (y1 < H_);
            const bool vx0 = (x0 >= 0) & (x0 < W_);
            const bool vx1 = (x1 >= 0) & (x1 < W_);
            const int cy0 = min(max(y0, 0), H_ - 1);
            const int cy1 = min(max(y1, 0), H_ - 1);
            const int cx0 = min(max(x0, 0), W_ - 1);
            const int cx1 = min(max(x1, 0), W_ - 1);

            float* q = &lds[wv][e][0];
            q[0] = (1.f - ly) * (1.f - lx) * mval * ((vy0 && vx0) ? 1.f : 0.f);
            q[1] = (1.f - ly) * lx         * mval * ((vy0 && vx1) ? 1.f : 0.f);
            q[2] = ly         * (1.f - lx) * mval * ((vy1 && vx0) ? 1.f : 0.f);
            q[3] = ly         * lx         * mval * ((vy1 && vx1) ? 1.f : 0.f);
            int* qi = (int*)q;
            qi[4] = cy0 * W_ + cx0;
            qi[5] = cy0 * W_ + cx1;
            qi[6] = cy1 * W_ + cx0;
            qi[7] = cy1 * W_ + cx1;
        }
    }
    __syncthreads();

    // ---- phase 2: lane = channel, wave-uniform fp32 gathers ----
    const float* xb = xh + ((size_t)n * HW_) * 64 + lane;
    for (int p = 0; p < 8; ++p) {
        const int px = px0 + p;
        u16* cp = cols2 + (size_t)px * KK_ + lane;
#pragma unroll
        for (int t = 0; t < K_; ++t) {
            const float* q = &lds[wv][p * 9 + t][0];
            const v4f f = *(const v4f*)q;                   // broadcast b128
            const v4i o = *(const v4i*)(q + 4);             // broadcast b128

            const float v00 = xb[(size_t)o.x * 64];         // 256B uniform loads
            const float v01 = xb[(size_t)o.y * 64];
            const float v10 = xb[(size_t)o.z * 64];
            const float v11 = xb[(size_t)o.w * 64];

            const float val = fmaf(f.x, v00, fmaf(f.y, v01,
                              fmaf(f.z, v10, f.w * v11)));
            cp[t * 64] = f2bf(val);                         // 128B wave store
        }
    }
}

// ---------------------------------------------------------------------------
// GEMM: out[o, px] = sum_k wA3[o,k] * cols2[px,k].  M=64, K=576, N=65536.
// Block = 4 waves covering 64cout x 64px; wave tile = 32cout x 32px (2x2 of
// 16x16x32). Grid 1024 -> 4 blocks/CU = 4 waves/SIMD (hides cols2 B-stream).
// Same XCD swizzle as im2col -> cols2 slab L2 affinity. No LDS, no barriers.
// ---------------------------------------------------------------------------
__global__ __launch_bounds__(256) void gemm_mfma(
    const u16* __restrict__ cols2,     // (NPIX, KK)
    const u16* __restrict__ wA3,       // (COUT, KK)
    const float* __restrict__ bias,
    float* __restrict__ out)           // (N, Cout, H, W)
{
    const int lane = threadIdx.x & 63;
    const int wv   = threadIdx.x >> 6;
    const int quad = lane >> 4;
    const int l16  = lane & 15;

    const int lb  = (blockIdx.x & 7) * 128 + (blockIdx.x >> 3);  // match im2col
    const int pxb = lb * 64;
    const int n   = pxb >> 14;                   // 64 | HW_: never crosses
    const int mb  = (wv & 1) * 32;               // wave's cout half
    const int pxw = pxb + (wv >> 1) * 32;        // wave's 32-pixel strip
    const int hwb = pxw & (HW_ - 1);

    v4f acc[2][2];
#pragma unroll
    for (int mh = 0; mh < 2; ++mh)
#pragma unroll
        for (int nh = 0; nh < 2; ++nh)
            acc[mh][nh] = (v4f){0.f, 0.f, 0.f, 0.f};

    const u16* bp0 = cols2 + (size_t)(pxw + l16) * KK_ + quad * 8;
    const u16* bp1 = bp0 + 16 * KK_;
    const u16* ap  = wA3 + (size_t)(mb + l16) * KK_ + quad * 8;

    for (int kc = 0; kc < KK_ / 32; ++kc) {      // 18 chunks of 32
        v8s bfr[2];
        bfr[0] = *(const v8s*)(bp0 + kc * 32);
        bfr[1] = *(const v8s*)(bp1 + kc * 32);
        v8s afr[2];
        afr[0] = *(const v8s*)(ap + kc * 32);
        afr[1] = *(const v8s*)(ap + 16 * KK_ + kc * 32);
#pragma unroll
        for (int mh = 0; mh < 2; ++mh)
#pragma unroll
            for (int nh = 0; nh < 2; ++nh)
                acc[mh][nh] = __builtin_amdgcn_mfma_f32_16x16x32_bf16(
                    afr[mh], bfr[nh], acc[mh][nh], 0, 0, 0);
    }

    // D layout (R4-verified): col = l16 (px), row = quad*4 + r (cout)
    float* outb = out + n * (COUT_ * HW_);
#pragma unroll
    for (int mh = 0; mh < 2; ++mh)
#pragma unroll
        for (int nh = 0; nh < 2; ++nh)
#pragma unroll
            for (int r = 0; r < 4; ++r) {
                const int m = mb + mh * 16 + quad * 4 + r;
                outb[m * HW_ + hwb + nh * 16 + l16] = acc[mh][nh][r] + bias[m];
            }
}

// ---------------------------------------------------------------------------
// Fallback (ws too small): R3-style direct fp32 kernel, no ws needed.
// ---------------------------------------------------------------------------
__global__ __launch_bounds__(256) void dcn_fallback(
    const float* __restrict__ x, const float* __restrict__ offset,
    const float* __restrict__ mask, const float* __restrict__ wptr,
    const float* __restrict__ bias, float* __restrict__ out)
{
    const int pix = blockIdx.x * 256 + threadIdx.x;
    const int n = pix >> 14, hw = pix & (HW_ - 1);
    const int ho = hw >> 7,  wo = hw & (W_ - 1);
    float acc[COUT_];
#pragma unroll
    for (int o = 0; o < COUT_; ++o) acc[o] = bias[o];
    const float* xn   = x + n * (C_ * HW_);
    const float* offn = offset + n * (2 * K_ * HW_) + hw;
    const float* mn   = mask + n * (K_ * HW_) + hw;
    for (int ct = 0; ct < C_; ct += 8) {
        for (int k = 0; k < K_; ++k) {
            const int ky = k / KW_, kx = k - ky * KW_;
            const float off_y = offn[(2 * k + 0) * HW_];
            const float off_x = offn[(2 * k + 1) * HW_];
            const float m = mn[k * HW_];
            const float py = (float)(ho - 1 + ky) + off_y;
            const float px = (float)(wo - 1 + kx) + off_x;
            const float y0f = floorf(py), x0f = floorf(px);
            const float ly = py - y0f, lx = px - x0f;
            const int y0 = (int)y0f, x0 = (int)x0f, y1 = y0 + 1, x1 = x0 + 1;
            const bool vy0 = (y0 >= 0) & (y0 < H_), vy1 = (y1 >= 0) & (y1 < H_);
            const bool vx0 = (x0 >= 0) & (x0 < W_), vx1 = (x1 >= 0) & (x1 < W_);
            const int cy0 = min(max(y0, 0), H_ - 1), cy1 = min(max(y1, 0), H_ - 1);
            const int cx0 = min(max(x0, 0), W_ - 1), cx1 = min(max(x1, 0), W_ - 1);
            const int i00 = cy0 * W_ + cx0, i01 = cy0 * W_ + cx1;
            const int i10 = cy1 * W_ + cx0, i11 = cy1 * W_ + cx1;
            const float f00 = (1.f - ly) * (1.f - lx) * m * ((vy0 && vx0) ? 1.f : 0.f);
            const float f01 = (1.f - ly) * lx * m * ((vy0 && vx1) ? 1.f : 0.f);
            const float f10 = ly * (1.f - lx) * m * ((vy1 && vx0) ? 1.f : 0.f);
            const float f11 = ly * lx * m * ((vy1 && vx1) ? 1.f : 0.f);
            for (int cc = 0; cc < 8; ++cc) {
                const int c = ct + cc;
                const float* xc = xn + c * HW_;
                const float val = fmaf(f00, xc[i00], fmaf(f01, xc[i01],
                                  fmaf(f10, xc[i10], f11 * xc[i11])));
#pragma unroll
                for (int o = 0; o < COUT_; ++o)
                    acc[o] = fmaf(wptr[o * (C_ * K_) + c * K_ + k], val, acc[o]);
            }
        }
    }
    float* outp = out + n * (COUT_ * HW_) + hw;
#pragma unroll
    for (int o = 0; o < COUT_; ++o) outp[o * HW_] = acc[o];
}

extern "C" void kernel_launch(void* const* d_in, const int* in_sizes, int n_in,
                              void* d_out, int out_size, void* d_ws, size_t ws_size,
                              hipStream_t stream) {
    const float* x      = (const float*)d_in[0];
    const float* offset = (const float*)d_in[1];
    const float* mask   = (const float*)d_in[2];
    const float* weight = (const float*)d_in[3];
    const float* bias   = (const float*)d_in[4];
    float* out = (float*)d_out;

    const size_t cols_bytes = (size_t)NPIX * KK_ * sizeof(u16);      // 75.5 MB
    const size_t xh_bytes   = (size_t)NPIX * C_ * sizeof(float);     // 16.8 MB
    const size_t wA_bytes   = (size_t)COUT_ * KK_ * sizeof(u16);     // 73.7 KB

    if (ws_size >= cols_bytes + xh_bytes + wA_bytes) {
        u16*   cols2 = (u16*)d_ws;
        float* xh    = (float*)((char*)d_ws + cols_bytes);
        u16*   wA3   = (u16*)((char*)d_ws + cols_bytes + xh_bytes);
        prep<<<1024 + 144, 256, 0, stream>>>(x, xh, weight, wA3);
        im2col<<<NPIX / 32, 256, 0, stream>>>(xh, offset, mask, cols2);
        gemm_mfma<<<NPIX / 64, 256, 0, stream>>>(cols2, wA3, bias, out);
    } else {
        dcn_fallback<<<NPIX / 256, 256, 0, stream>>>(x, offset, mask, weight, bias, out);
    }
}

// Round 10
// 133.261 us; speedup vs baseline: 1.2796x; 1.1136x over previous
//
#include <hip/hip_runtime.h>

// DCNv2 forward = prep (weight repack + NHWC transpose) + FUSED
// im2col+GEMM (2-phase coefs, lane=channel wave-uniform gathers,
// double-buffered LDS B-tile, 1 barrier/tap, MFMA 32x32 wave tiles).
#define N_    4
#define C_    64
#define H_    128
#define W_    128
#define KW_   3
#define K_    9
#define COUT_ 64
#define HW_   (H_ * W_)     // 16384
#define NPIX  (N_ * HW_)    // 65536
#define KK_   (C_ * K_)     // 576

typedef short v8s __attribute__((ext_vector_type(8)));   // 8 bf16 (4 VGPRs)
typedef float v4f __attribute__((ext_vector_type(4)));   // MFMA C/D
typedef int   v4i __attribute__((ext_vector_type(4)));
typedef unsigned short u16;

static __device__ __forceinline__ u16 f2bf(float f) {
    union { float f; unsigned int u; } v; v.f = f;
    unsigned int r = v.u + 0x7FFFu + ((v.u >> 16) & 1u);   // RNE
    return (u16)(r >> 16);
}

// ---------------------------------------------------------------------------
// prep: one dispatch doing both prologue jobs.
//   blocks 0..1023  : NCHW->NHWC fp32 transpose xh[n][hw][c] (LDS-tiled 64x64)
//   blocks 1024..1167: wA3[o][k] = bf16(weight[o][c][tap]), k = tap*64+c
// ---------------------------------------------------------------------------
__global__ __launch_bounds__(256) void prep(
    const float* __restrict__ x, float* __restrict__ xh,
    const float* __restrict__ w, u16* __restrict__ wA3)
{
    if (blockIdx.x < 1024) {
        const int n   = blockIdx.x >> 8;            // 4 images x 256 hw-tiles
        const int hw0 = (blockIdx.x & 255) * 64;
        const int j   = threadIdx.x & 63;           // lane
        const int r0  = threadIdx.x >> 6;           // 0..3

        __shared__ float tile[64][65];              // [hw][c], pad -> conflict-free
        const float* xb = x + n * (C_ * HW_);
#pragma unroll
        for (int i = 0; i < 16; ++i) {
            const int c = i * 4 + r0;
            tile[j][c] = xb[c * HW_ + hw0 + j];     // lane j = hw: coalesced 256B
        }
        __syncthreads();
        float* xo = xh + ((size_t)n * HW_ + hw0) * 64;
#pragma unroll
        for (int i = 0; i < 16; ++i) {
            const int hr = i * 4 + r0;
            xo[hr * 64 + j] = tile[hr][j];          // lane j = c: coalesced 256B
        }
    } else {
        const int tid = (blockIdx.x - 1024) * 256 + threadIdx.x;  // 0..36863
        if (tid < COUT_ * KK_) {
            const int k   = tid % KK_;              // tap*64 + c
            const int o   = tid / KK_;
            const int c   = k & 63;
            const int tap = k >> 6;
            wA3[tid] = f2bf(w[o * (C_ * K_) + c * K_ + tap]);
        }
    }
}

// ---------------------------------------------------------------------------
// Fused im2col+GEMM. Block = 256 thr / 4 waves, covers 64 px x 64 cout.
// Phase 1 (once per block): all 576 (px,tap) bilinear coef sets, lane-
// parallel, -> 18.4 KB LDS.  (R7-verified math; one-time 16-way write
// conflicts on 32B-stride b128 stores are ~1% of block time.)
// Main loop over 9 taps, double-buffered 64px x 64c bf16 B-tile in LDS
// (inner dim padded 64->72: MFMA b128 reads 2-way banks = free):
//   gather(t+1): wave gathers 16 px via wave-uniform 256B corner loads
//   MFMA(t):     2 k-chunks x 2x2 of 16x16x32, A-frags 16B from wA3 (L1)
//   ONE barrier per tap (dbuf removes the R4 gather->MFMA drain).
// cols never touches HBM: saves im2col's 75.5 MB write + GEMM's read.
// ---------------------------------------------------------------------------
__global__ __launch_bounds__(256, 4) void dcn_fused(
    const float* __restrict__ xh,      // (N, HW, C) fp32
    const float* __restrict__ offset,  // (N, 2*K, H, W)
    const float* __restrict__ mask,    // (N, K, H, W)
    const u16* __restrict__ wA3,       // (COUT, KK) bf16, k = tap*64+c
    const float* __restrict__ bias,
    float* __restrict__ out)           // (N, Cout, H, W)
{
    const int tid  = threadIdx.x;
    const int lane = tid & 63;
    const int wv   = tid >> 6;
    const int quad = lane >> 4;
    const int l16  = lane & 15;

    const int lb  = (blockIdx.x & 7) * 128 + (blockIdx.x >> 3);  // XCD swizzle
    const int pxb = lb * 64;                     // 64 | HW_: one image per block
    const int n   = pxb >> 14;
    const int hwb = pxb & (HW_ - 1);

    __shared__ float coef[576][8];               // 18.4 KB [p*9+t][f4,i4]
    __shared__ u16   Bt[2][64][72];              // 18.4 KB [buf][px][c pad 72]

    // ---- phase 1: all coefs for this block's 64 px x 9 taps ----
#pragma unroll
    for (int r = 0; r < 3; ++r) {
        const int e = tid + 256 * r;
        if (e < 576) {
            const int p  = e / 9;                // magic-mul
            const int t  = e - p * 9;
            const int hw = hwb + p;
            const int ho = hw >> 7;
            const int wo = hw & (W_ - 1);
            const int ky = t / KW_;
            const int kx = t - ky * KW_;

            const float offy = offset[n * (2 * K_ * HW_) + (2 * t + 0) * HW_ + hw];
            const float offx = offset[n * (2 * K_ * HW_) + (2 * t + 1) * HW_ + hw];
            const float mval = mask[n * (K_ * HW_) + t * HW_ + hw];

            const float py = (float)(ho - 1 + ky) + offy;   // stride=1,pad=1,dil=1
            const float qx = (float)(wo - 1 + kx) + offx;
            const float y0f = floorf(py), x0f = floorf(qx);
            const float ly = py - y0f, lx = qx - x0f;
            const int y0 = (int)y0f, x0 = (int)x0f;
            const int y1 = y0 + 1,   x1 = x0 + 1;
            const bool vy0 = (y0 >= 0) & (y0 < H_);
            const bool vy1 = (y1 >= 0) & (y1 < H_);
            const bool vx0 = (x0 >= 0) & (x0 < W_);
            const bool vx1 = (x1 >= 0) & (x1 < W_);
            const int cy0 = min(max(y0, 0), H_ - 1);
            const int cy1 = min(max(y1, 0), H_ - 1);
            const int cx0 = min(max(x0, 0), W_ - 1);
            const int cx1 = min(max(x1, 0), W_ - 1);

            float* q = &coef[e][0];
            q[0] = (1.f - ly) * (1.f - lx) * mval * ((vy0 && vx0) ? 1.f : 0.f);
            q[1] = (1.f - ly) * lx         * mval * ((vy0 && vx1) ? 1.f : 0.f);
            q[2] = ly         * (1.f - lx) * mval * ((vy1 && vx0) ? 1.f : 0.f);
            q[3] = ly         * lx         * mval * ((vy1 && vx1) ? 1.f : 0.f);
            int* qi = (int*)q;
            qi[4] = cy0 * W_ + cx0;
            qi[5] = cy0 * W_ + cx1;
            qi[6] = cy1 * W_ + cx0;
            qi[7] = cy1 * W_ + cx1;
        }
    }
    __syncthreads();

    const float* xb = xh + ((size_t)n * HW_) * 64 + lane;   // lane = channel

    // wave's MFMA identity: cout half x pixel half
    const int mb   = (wv & 1) * 32;
    const int pxwl = (wv >> 1) * 32;             // local pixel base for MFMA

    v4f acc[2][2];
#pragma unroll
    for (int mh = 0; mh < 2; ++mh)
#pragma unroll
        for (int nh = 0; nh < 2; ++nh)
            acc[mh][nh] = (v4f){0.f, 0.f, 0.f, 0.f};

    // gather tap t into buffer b: wave covers px_local wv*16 .. wv*16+15
#define GATHER(t, b)                                                        \
    {                                                                       \
        _Pragma("unroll")                                                   \
        for (int i = 0; i < 16; ++i) {                                      \
            const int p = wv * 16 + i;                                      \
            const float* q = &coef[p * 9 + (t)][0];                         \
            const v4f f = *(const v4f*)q;                                   \
            const v4i o = *(const v4i*)(q + 4);                             \
            const float v00 = xb[(size_t)o.x * 64];                         \
            const float v01 = xb[(size_t)o.y * 64];                         \
            const float v10 = xb[(size_t)o.z * 64];                         \
            const float v11 = xb[(size_t)o.w * 64];                         \
            const float val = fmaf(f.x, v00, fmaf(f.y, v01,                 \
                              fmaf(f.z, v10, f.w * v11)));                  \
            Bt[b][p][lane] = f2bf(val);                                     \
        }                                                                   \
    }

    GATHER(0, 0)
    __syncthreads();

    for (int t = 0; t < K_; ++t) {
        const int buf = t & 1;
        if (t < K_ - 1) GATHER(t + 1, buf ^ 1)

        // MFMA(t): A-frags from wA3 (k = t*64 + kc*32 + quad*8), B from Bt
#pragma unroll
        for (int kc = 0; kc < 2; ++kc) {
            v8s bfr[2];
#pragma unroll
            for (int nh = 0; nh < 2; ++nh)
                bfr[nh] = *(const v8s*)&Bt[buf][pxwl + nh * 16 + l16][kc * 32 + quad * 8];
            v8s afr[2];
#pragma unroll
            for (int mh = 0; mh < 2; ++mh)
                afr[mh] = *(const v8s*)(wA3 + (size_t)(mb + mh * 16 + l16) * KK_
                                            + t * 64 + kc * 32 + quad * 8);
#pragma unroll
            for (int mh = 0; mh < 2; ++mh)
#pragma unroll
                for (int nh = 0; nh < 2; ++nh)
                    acc[mh][nh] = __builtin_amdgcn_mfma_f32_16x16x32_bf16(
                        afr[mh], bfr[nh], acc[mh][nh], 0, 0, 0);
        }
        __syncthreads();   // MFMA(t) reads done AND gather(t+1) writes done
    }
#undef GATHER

    // D layout (R4-verified): col = l16 (px), row = quad*4 + r (cout)
    float* outb = out + n * (COUT_ * HW_);
#pragma unroll
    for (int mh = 0; mh < 2; ++mh)
#pragma unroll
        for (int nh = 0; nh < 2; ++nh)
#pragma unroll
            for (int r = 0; r < 4; ++r) {
                const int m = mb + mh * 16 + quad * 4 + r;
                outb[m * HW_ + hwb + pxwl + nh * 16 + l16] = acc[mh][nh][r] + bias[m];
            }
}

// ---------------------------------------------------------------------------
// Fallback (ws too small): R3-style direct fp32 kernel, no ws needed.
// ---------------------------------------------------------------------------
__global__ __launch_bounds__(256) void dcn_fallback(
    const float* __restrict__ x, const float* __restrict__ offset,
    const float* __restrict__ mask, const float* __restrict__ wptr,
    const float* __restrict__ bias, float* __restrict__ out)
{
    const int pix = blockIdx.x * 256 + threadIdx.x;
    const int n = pix >> 14, hw = pix & (HW_ - 1);
    const int ho = hw >> 7,  wo = hw & (W_ - 1);
    float acc[COUT_];
#pragma unroll
    for (int o = 0; o < COUT_; ++o) acc[o] = bias[o];
    const float* xn   = x + n * (C_ * HW_);
    const float* offn = offset + n * (2 * K_ * HW_) + hw;
    const float* mn   = mask + n * (K_ * HW_) + hw;
    for (int ct = 0; ct < C_; ct += 8) {
        for (int k = 0; k < K_; ++k) {
            const int ky = k / KW_, kx = k - ky * KW_;
            const float off_y = offn[(2 * k + 0) * HW_];
            const float off_x = offn[(2 * k + 1) * HW_];
            const float m = mn[k * HW_];
            const float py = (float)(ho - 1 + ky) + off_y;
            const float px = (float)(wo - 1 + kx) + off_x;
            const float y0f = floorf(py), x0f = floorf(px);
            const float ly = py - y0f, lx = px - x0f;
            const int y0 = (int)y0f, x0 = (int)x0f, y1 = y0 + 1, x1 = x0 + 1;
            const bool vy0 = (y0 >= 0) & (y0 < H_), vy1 = (y1 >= 0) & (y1 < H_);
            const bool vx0 = (x0 >= 0) & (x0 < W_), vx1 = (x1 >= 0) & (x1 < W_);
            const int cy0 = min(max(y0, 0), H_ - 1), cy1 = min(max(y1, 0), H_ - 1);
            const int cx0 = min(max(x0, 0), W_ - 1), cx1 = min(max(x1, 0), W_ - 1);
            const int i00 = cy0 * W_ + cx0, i01 = cy0 * W_ + cx1;
            const int i10 = cy1 * W_ + cx0, i11 = cy1 * W_ + cx1;
            const float f00 = (1.f - ly) * (1.f - lx) * m * ((vy0 && vx0) ? 1.f : 0.f);
            const float f01 = (1.f - ly) * lx * m * ((vy0 && vx1) ? 1.f : 0.f);
            const float f10 = ly * (1.f - lx) * m * ((vy1 && vx0) ? 1.f : 0.f);
            const float f11 = ly * lx * m * ((vy1 && vx1) ? 1.f : 0.f);
            for (int cc = 0; cc < 8; ++cc) {
                const int c = ct + cc;
                const float* xc = xn + c * HW_;
                const float val = fmaf(f00, xc[i00], fmaf(f01, xc[i01],
                                  fmaf(f10, xc[i10], f11 * xc[i11])));
#pragma unroll
                for (int o = 0; o < COUT_; ++o)
                    acc[o] = fmaf(wptr[o * (C_ * K_) + c * K_ + k], val, acc[o]);
            }
        }
    }
    float* outp = out + n * (COUT_ * HW_) + hw;
#pragma unroll
    for (int o = 0; o < COUT_; ++o) outp[o * HW_] = acc[o];
}

extern "C" void kernel_launch(void* const* d_in, const int* in_sizes, int n_in,
                              void* d_out, int out_size, void* d_ws, size_t ws_size,
                              hipStream_t stream) {
    const float* x      = (const float*)d_in[0];
    const float* offset = (const float*)d_in[1];
    const float* mask   = (const float*)d_in[2];
    const float* weight = (const float*)d_in[3];
    const float* bias   = (const float*)d_in[4];
    float* out = (float*)d_out;

    const size_t xh_bytes = (size_t)NPIX * C_ * sizeof(float);     // 16.8 MB
    const size_t wA_bytes = (size_t)COUT_ * KK_ * sizeof(u16);     // 73.7 KB

    if (ws_size >= xh_bytes + wA_bytes) {
        float* xh  = (float*)d_ws;
        u16*   wA3 = (u16*)((char*)d_ws + xh_bytes);
        prep<<<1024 + 144, 256, 0, stream>>>(x, xh, weight, wA3);
        dcn_fused<<<NPIX / 64, 256, 0, stream>>>(xh, offset, mask, wA3, bias, out);
    } else {
        dcn_fallback<<<NPIX / 256, 256, 0, stream>>>(x, offset, mask, weight, bias, out);
    }
}

// Round 12
// 121.510 us; speedup vs baseline: 1.4033x; 1.0967x over previous
//
#include <hip/hip_runtime.h>

// DCNv2 forward = prep (weight repack + NHWC transpose) + FUSED
// im2col+GEMM. R11: quarter-wave-per-pixel gather (float4 = 4 channels/lane,
// 16B sweet spot) -> 4x fewer VMEM/LDS requests in the gather phase.
// (R12 = identical resubmit of R11: container infra failure, never ran.)
#define N_    4
#define C_    64
#define H_    128
#define W_    128
#define KW_   3
#define K_    9
#define COUT_ 64
#define HW_   (H_ * W_)     // 16384
#define NPIX  (N_ * HW_)    // 65536
#define KK_   (C_ * K_)     // 576

typedef short v8s __attribute__((ext_vector_type(8)));   // 8 bf16 (4 VGPRs)
typedef float v4f __attribute__((ext_vector_type(4)));   // MFMA C/D
typedef int   v4i __attribute__((ext_vector_type(4)));
typedef unsigned int u32;
typedef unsigned short u16;
typedef unsigned int v2u __attribute__((ext_vector_type(2)));

static __device__ __forceinline__ u16 f2bf(float f) {
    union { float f; unsigned int u; } v; v.f = f;
    unsigned int r = v.u + 0x7FFFu + ((v.u >> 16) & 1u);   // RNE
    return (u16)(r >> 16);
}
static __device__ __forceinline__ u32 pack2(float lo, float hi) {
    return ((u32)f2bf(hi) << 16) | (u32)f2bf(lo);
}

// ---------------------------------------------------------------------------
// prep: one dispatch doing both prologue jobs.
//   blocks 0..1023  : NCHW->NHWC fp32 transpose xh[n][hw][c] (LDS-tiled 64x64)
//   blocks 1024..1167: wA3[o][k] = bf16(weight[o][c][tap]), k = tap*64+c
// ---------------------------------------------------------------------------
__global__ __launch_bounds__(256) void prep(
    const float* __restrict__ x, float* __restrict__ xh,
    const float* __restrict__ w, u16* __restrict__ wA3)
{
    if (blockIdx.x < 1024) {
        const int n   = blockIdx.x >> 8;            // 4 images x 256 hw-tiles
        const int hw0 = (blockIdx.x & 255) * 64;
        const int j   = threadIdx.x & 63;           // lane
        const int r0  = threadIdx.x >> 6;           // 0..3

        __shared__ float tile[64][65];              // [hw][c], pad -> conflict-free
        const float* xb = x + n * (C_ * HW_);
#pragma unroll
        for (int i = 0; i < 16; ++i) {
            const int c = i * 4 + r0;
            tile[j][c] = xb[c * HW_ + hw0 + j];     // lane j = hw: coalesced 256B
        }
        __syncthreads();
        float* xo = xh + ((size_t)n * HW_ + hw0) * 64;
#pragma unroll
        for (int i = 0; i < 16; ++i) {
            const int hr = i * 4 + r0;
            xo[hr * 64 + j] = tile[hr][j];          // lane j = c: coalesced 256B
        }
    } else {
        const int tid = (blockIdx.x - 1024) * 256 + threadIdx.x;  // 0..36863
        if (tid < COUT_ * KK_) {
            const int k   = tid % KK_;              // tap*64 + c
            const int o   = tid / KK_;
            const int c   = k & 63;
            const int tap = k >> 6;
            wA3[tid] = f2bf(w[o * (C_ * K_) + c * K_ + tap]);
        }
    }
}

// ---------------------------------------------------------------------------
// Fused im2col+GEMM. Block = 256 thr / 4 waves, covers 64 px x 64 cout.
// Phase 1 (once per block): all 576 (px,tap) bilinear coef sets -> 18.4 KB LDS.
// Main loop over 9 taps, double-buffered 64px x 64c bf16 B-tile in LDS:
//   gather(t+1): quarter-wave per pixel — lane = (qtr, c4); each lane loads
//     float4 (4 channels) per corner; one instruction covers 4 pixels' corner.
//     16 dwordx4 loads + 8 coef b128 + 4 ds_write_b64 per wave per tap
//     (R10: 64 dword loads + 32 b128 + 16 u16 writes — 4x the requests).
//   MFMA(t): 2 k-chunks x 2x2 of 16x16x32, A-frags 16B from wA3 (L1-hot).
//   ONE barrier per tap.
// ---------------------------------------------------------------------------
__global__ __launch_bounds__(256, 4) void dcn_fused(
    const float* __restrict__ xh,      // (N, HW, C) fp32
    const float* __restrict__ offset,  // (N, 2*K, H, W)
    const float* __restrict__ mask,    // (N, K, H, W)
    const u16* __restrict__ wA3,       // (COUT, KK) bf16, k = tap*64+c
    const float* __restrict__ bias,
    float* __restrict__ out)           // (N, Cout, H, W)
{
    const int tid  = threadIdx.x;
    const int lane = tid & 63;
    const int wv   = tid >> 6;
    const int quad = lane >> 4;
    const int l16  = lane & 15;

    const int lb  = (blockIdx.x & 7) * 128 + (blockIdx.x >> 3);  // XCD swizzle
    const int pxb = lb * 64;                     // 64 | HW_: one image per block
    const int n   = pxb >> 14;
    const int hwb = pxb & (HW_ - 1);

    __shared__ float coef[576][8];               // 18.4 KB [p*9+t][f4,i4]
    __shared__ u16   Bt[2][64][72];              // 18.4 KB [buf][px][c pad 72]

    // ---- phase 1: all coefs for this block's 64 px x 9 taps ----
#pragma unroll
    for (int r = 0; r < 3; ++r) {
        const int e = tid + 256 * r;
        if (e < 576) {
            const int p  = e / 9;                // magic-mul
            const int t  = e - p * 9;
            const int hw = hwb + p;
            const int ho = hw >> 7;
            const int wo = hw & (W_ - 1);
            const int ky = t / KW_;
            const int kx = t - ky * KW_;

            const float offy = offset[n * (2 * K_ * HW_) + (2 * t + 0) * HW_ + hw];
            const float offx = offset[n * (2 * K_ * HW_) + (2 * t + 1) * HW_ + hw];
            const float mval = mask[n * (K_ * HW_) + t * HW_ + hw];

            const float py = (float)(ho - 1 + ky) + offy;   // stride=1,pad=1,dil=1
            const float qx = (float)(wo - 1 + kx) + offx;
            const float y0f = floorf(py), x0f = floorf(qx);
            const float ly = py - y0f, lx = qx - x0f;
            const int y0 = (int)y0f, x0 = (int)x0f;
            const int y1 = y0 + 1,   x1 = x0 + 1;
            const bool vy0 = (y0 >= 0) & (y0 < H_);
            const bool vy1 = (y1 >= 0) & (y1 < H_);
            const bool vx0 = (x0 >= 0) & (x0 < W_);
            const bool vx1 = (x1 >= 0) & (x1 < W_);
            const int cy0 = min(max(y0, 0), H_ - 1);
            const int cy1 = min(max(y1, 0), H_ - 1);
            const int cx0 = min(max(x0, 0), W_ - 1);
            const int cx1 = min(max(x1, 0), W_ - 1);

            float* q = &coef[e][0];
            q[0] = (1.f - ly) * (1.f - lx) * mval * ((vy0 && vx0) ? 1.f : 0.f);
            q[1] = (1.f - ly) * lx         * mval * ((vy0 && vx1) ? 1.f : 0.f);
            q[2] = ly         * (1.f - lx) * mval * ((vy1 && vx0) ? 1.f : 0.f);
            q[3] = ly         * lx         * mval * ((vy1 && vx1) ? 1.f : 0.f);
            int* qi = (int*)q;
            qi[4] = cy0 * W_ + cx0;
            qi[5] = cy0 * W_ + cx1;
            qi[6] = cy1 * W_ + cx0;
            qi[7] = cy1 * W_ + cx1;
        }
    }
    __syncthreads();

    // gather identity: quarter-wave per pixel, 4 channels per lane
    const int qtr = lane >> 4;                   // pixel within group of 4
    const int c4  = lane & 15;                   // channel quad: 4c4..4c4+3
    const float* xb4 = xh + ((size_t)n * HW_) * 64 + 4 * c4;

    // wave's MFMA identity: cout half x pixel half
    const int mb   = (wv & 1) * 32;
    const int pxwl = (wv >> 1) * 32;             // local pixel base for MFMA

    v4f acc[2][2];
#pragma unroll
    for (int mh = 0; mh < 2; ++mh)
#pragma unroll
        for (int nh = 0; nh < 2; ++nh)
            acc[mh][nh] = (v4f){0.f, 0.f, 0.f, 0.f};

    // gather tap t into buffer b: wave covers px_local wv*16 .. wv*16+15
#define GATHER(t, b)                                                        \
    {                                                                       \
        _Pragma("unroll")                                                   \
        for (int i = 0; i < 4; ++i) {                                       \
            const int p = wv * 16 + 4 * i + qtr;                            \
            const float* q = &coef[p * 9 + (t)][0];                         \
            const v4f f = *(const v4f*)q;                                   \
            const v4i o = *(const v4i*)(q + 4);                             \
            const v4f v00 = *(const v4f*)(xb4 + (size_t)o.x * 64);          \
            const v4f v01 = *(const v4f*)(xb4 + (size_t)o.y * 64);          \
            const v4f v10 = *(const v4f*)(xb4 + (size_t)o.z * 64);          \
            const v4f v11 = *(const v4f*)(xb4 + (size_t)o.w * 64);          \
            float r0 = fmaf(f.x, v00.x, fmaf(f.y, v01.x,                    \
                       fmaf(f.z, v10.x, f.w * v11.x)));                     \
            float r1 = fmaf(f.x, v00.y, fmaf(f.y, v01.y,                    \
                       fmaf(f.z, v10.y, f.w * v11.y)));                     \
            float r2 = fmaf(f.x, v00.z, fmaf(f.y, v01.z,                    \
                       fmaf(f.z, v10.z, f.w * v11.z)));                     \
            float r3 = fmaf(f.x, v00.w, fmaf(f.y, v01.w,                    \
                       fmaf(f.z, v10.w, f.w * v11.w)));                     \
            v2u pk;                                                         \
            pk.x = pack2(r0, r1);                                           \
            pk.y = pack2(r2, r3);                                           \
            *(v2u*)&Bt[b][p][4 * c4] = pk;                                  \
        }                                                                   \
    }

    GATHER(0, 0)
    __syncthreads();

    for (int t = 0; t < K_; ++t) {
        const int buf = t & 1;
        if (t < K_ - 1) GATHER(t + 1, buf ^ 1)

        // MFMA(t): A-frags from wA3 (k = t*64 + kc*32 + quad*8), B from Bt
#pragma unroll
        for (int kc = 0; kc < 2; ++kc) {
            v8s bfr[2];
#pragma unroll
            for (int nh = 0; nh < 2; ++nh)
                bfr[nh] = *(const v8s*)&Bt[buf][pxwl + nh * 16 + l16][kc * 32 + quad * 8];
            v8s afr[2];
#pragma unroll
            for (int mh = 0; mh < 2; ++mh)
                afr[mh] = *(const v8s*)(wA3 + (size_t)(mb + mh * 16 + l16) * KK_
                                            + t * 64 + kc * 32 + quad * 8);
#pragma unroll
            for (int mh = 0; mh < 2; ++mh)
#pragma unroll
                for (int nh = 0; nh < 2; ++nh)
                    acc[mh][nh] = __builtin_amdgcn_mfma_f32_16x16x32_bf16(
                        afr[mh], bfr[nh], acc[mh][nh], 0, 0, 0);
        }
        __syncthreads();   // MFMA(t) reads done AND gather(t+1) writes done
    }
#undef GATHER

    // D layout (R4-verified): col = l16 (px), row = quad*4 + r (cout)
    float* outb = out + n * (COUT_ * HW_);
#pragma unroll
    for (int mh = 0; mh < 2; ++mh)
#pragma unroll
        for (int nh = 0; nh < 2; ++nh)
#pragma unroll
            for (int r = 0; r < 4; ++r) {
                const int m = mb + mh * 16 + quad * 4 + r;
                outb[m * HW_ + hwb + pxwl + nh * 16 + l16] = acc[mh][nh][r] + bias[m];
            }
}

// ---------------------------------------------------------------------------
// Fallback (ws too small): R3-style direct fp32 kernel, no ws needed.
// ---------------------------------------------------------------------------
__global__ __launch_bounds__(256) void dcn_fallback(
    const float* __restrict__ x, const float* __restrict__ offset,
    const float* __restrict__ mask, const float* __restrict__ wptr,
    const float* __restrict__ bias, float* __restrict__ out)
{
    const int pix = blockIdx.x * 256 + threadIdx.x;
    const int n = pix >> 14, hw = pix & (HW_ - 1);
    const int ho = hw >> 7,  wo = hw & (W_ - 1);
    float acc[COUT_];
#pragma unroll
    for (int o = 0; o < COUT_; ++o) acc[o] = bias[o];
    const float* xn   = x + n * (C_ * HW_);
    const float* offn = offset + n * (2 * K_ * HW_) + hw;
    const float* mn   = mask + n * (K_ * HW_) + hw;
    for (int ct = 0; ct < C_; ct += 8) {
        for (int k = 0; k < K_; ++k) {
            const int ky = k / KW_, kx = k - ky * KW_;
            const float off_y = offn[(2 * k + 0) * HW_];
            const float off_x = offn[(2 * k + 1) * HW_];
            const float m = mn[k * HW_];
            const float py = (float)(ho - 1 + ky) + off_y;
            const float px = (float)(wo - 1 + kx) + off_x;
            const float y0f = floorf(py), x0f = floorf(px);
            const float ly = py - y0f, lx = px - x0f;
            const int y0 = (int)y0f, x0 = (int)x0f, y1 = y0 + 1, x1 = x0 + 1;
            const bool vy0 = (y0 >= 0) & (y0 < H_), vy1 = (y1 >= 0) & (y1 < H_);
            const bool vx0 = (x0 >= 0) & (x0 < W_), vx1 = (x1 >= 0) & (x1 < W_);
            const int cy0 = min(max(y0, 0), H_ - 1), cy1 = min(max(y1, 0), H_ - 1);
            const int cx0 = min(max(x0, 0), W_ - 1), cx1 = min(max(x1, 0), W_ - 1);
            const int i00 = cy0 * W_ + cx0, i01 = cy0 * W_ + cx1;
            const int i10 = cy1 * W_ + cx0, i11 = cy1 * W_ + cx1;
            const float f00 = (1.f - ly) * (1.f - lx) * m * ((vy0 && vx0) ? 1.f : 0.f);
            const float f01 = (1.f - ly) * lx * m * ((vy0 && vx1) ? 1.f : 0.f);
            const float f10 = ly * (1.f - lx) * m * ((vy1 && vx0) ? 1.f : 0.f);
            const float f11 = ly * lx * m * ((vy1 && vx1) ? 1.f : 0.f);
            for (int cc = 0; cc < 8; ++cc) {
                const int c = ct + cc;
                const float* xc = xn + c * HW_;
                const float val = fmaf(f00, xc[i00], fmaf(f01, xc[i01],
                                  fmaf(f10, xc[i10], f11 * xc[i11])));
#pragma unroll
                for (int o = 0; o < COUT_; ++o)
                    acc[o] = fmaf(wptr[o * (C_ * K_) + c * K_ + k], val, acc[o]);
            }
        }
    }
    float* outp = out + n * (COUT_ * HW_) + hw;
#pragma unroll
    for (int o = 0; o < COUT_; ++o) outp[o * HW_] = acc[o];
}

extern "C" void kernel_launch(void* const* d_in, const int* in_sizes, int n_in,
                              void* d_out, int out_size, void* d_ws, size_t ws_size,
                              hipStream_t stream) {
    const float* x      = (const float*)d_in[0];
    const float* offset = (const float*)d_in[1];
    const float* mask   = (const float*)d_in[2];
    const float* weight = (const float*)d_in[3];
    const float* bias   = (const float*)d_in[4];
    float* out = (float*)d_out;

    const size_t xh_bytes = (size_t)NPIX * C_ * sizeof(float);     // 16.8 MB
    const size_t wA_bytes = (size_t)COUT_ * KK_ * sizeof(u16);     // 73.7 KB

    if (ws_size >= xh_bytes + wA_bytes) {
        float* xh  = (float*)d_ws;
        u16*   wA3 = (u16*)((char*)d_ws + xh_bytes);
        prep<<<1024 + 144, 256, 0, stream>>>(x, xh, weight, wA3);
        dcn_fused<<<NPIX / 64, 256, 0, stream>>>(xh, offset, mask, wA3, bias, out);
    } else {
        dcn_fallback<<<NPIX / 256, 256, 0, stream>>>(x, offset, mask, weight, bias, out);
    }
}